// Round 1
// 310.163 us; speedup vs baseline: 1.0018x; 1.0018x over previous
//
#include <hip/hip_runtime.h>
#include <hip/hip_fp16.h>

// GraphEmbedding2: 3-layer GCN (DGL GraphConv, norm='both') + per-graph mean pooling.
// N=50000 nodes, E=600000 edges, d=128, G=64 graphs.
// fp16 gather operands (R6); LDS-histogram degrees + LDS-cursor CSR fill (R5/R8,
// zero global atomics); MFMA GEMM fp16-in/fp32-acc (R9); 8-deep clamped gather MLP (R10);
// scan_top folded into scan_write (R13); HIST_S=64 (R14).
// R15: (a) transposed MFMA roles (A=W^T frag, B=node frag) -> thread owns 1 node x 32
// consecutive features: half4 8B stores (was 32x 2B scatter), ns scale = 1 load;
// (b) layer-3 GEMM fused with pooling (shfl_xor 16-node reduce + LDS bins + ~1 global
// atomic per graph/feature/block; global-atomic fallback if block spans >=8 graphs);
// X3 buffer + k_pool_partial + gcnt eliminated; gcnt recomputed in k_finalize by
// binary search on sorted graph_ids; (c) k_agg csr indices: 1 VMEM load of 16 idx by
// lane&15 + 8 shfl broadcasts (was 8x 32-way-duplicate VMEM loads): 16->9 VMEM/round.
// Reverted-for-cause: R7 fusion (occupancy+LDS conflicts), R11 range passes
// (no FETCH drop, serialized MLP), R13 HIST_S=32 (grid coverage).

#define DIM 128
#define GRAPHS 64

typedef _Float16 half8 __attribute__((ext_vector_type(8)));
typedef _Float16 half4 __attribute__((ext_vector_type(4)));
typedef float floatx4 __attribute__((ext_vector_type(4)));

// ---------------------------------------------------------------- degree histogram (LDS)
#define HIST_R 4
#define HIST_S 64
#define NPR 12500          // nodes per range (HIST_R * NPR = 50000)
#define LDSW (NPR / 2)     // 6250 u32 words, 25 KB LDS

__global__ __launch_bounds__(256) void k_hist(const int* __restrict__ src,
                                              const int* __restrict__ dst,
                                              unsigned* __restrict__ partial, int E) {
    __shared__ unsigned hist[LDSW];
    int b = blockIdx.x;
    int a = b / (HIST_R * HIST_S);       // 0: src, 1: dst
    int r = (b / HIST_S) % HIST_R;       // node range
    int s = b % HIST_S;                  // edge slice
    const int* arr = a ? dst : src;
    for (int i = threadIdx.x; i < LDSW; i += 256) hist[i] = 0;
    __syncthreads();
    int chunk = (E + HIST_S - 1) / HIST_S;
    int e0 = s * chunk;
    int e1 = min(e0 + chunk, E);
    unsigned base = (unsigned)(r * NPR);
    for (int i = e0 + threadIdx.x; i < e1; i += 256) {
        unsigned n = (unsigned)arr[i] - base;
        if (n < NPR) atomicAdd(&hist[n >> 1], 1u << ((n & 1) * 16));
    }
    __syncthreads();
    unsigned* outp = partial + ((size_t)(a * HIST_R + r) * HIST_S + s) * LDSW;
    for (int i = threadIdx.x; i < LDSW; i += 256) outp[i] = hist[i];
}

// ---------------------------------------------------------------- merge + block sums
// Blocks [0, nb): dst — nd, inc, per-256-node bsum. Blocks [nb, 2nb): src — ns.
__global__ __launch_bounds__(256) void k_hist_merge(const unsigned* __restrict__ partial,
                                                    float* __restrict__ ns,
                                                    float* __restrict__ nd,
                                                    int* __restrict__ inc,
                                                    int* __restrict__ bsum, int N) {
    __shared__ int sred[256];
    int nb = (N + 255) / 256;
    int isDst = (blockIdx.x < nb) ? 1 : 0;
    int cb = isDst ? blockIdx.x : blockIdx.x - nb;
    int n = cb * 256 + threadIdx.x;
    int deg = 0;
    if (n < N) {
        int a = isDst ? 1 : 0;
        int r = n / NPR;
        int w = (n % NPR) >> 1;
        int field = (n & 1) * 16;
        const unsigned* p = partial + ((size_t)(a * HIST_R + r) * HIST_S) * LDSW + w;
        unsigned sum = 0;
#pragma unroll
        for (int s = 0; s < HIST_S; ++s) sum += p[(size_t)s * LDSW];
        deg = (int)((sum >> field) & 0xFFFFu);
        float nrm = rsqrtf(fmaxf((float)deg, 1.0f));
        if (isDst) { nd[n] = nrm; inc[n] = deg; }
        else       { ns[n] = nrm; }
    }
    if (isDst) {
        sred[threadIdx.x] = deg;
        __syncthreads();
        for (int off = 128; off > 0; off >>= 1) {
            if (threadIdx.x < off) sred[threadIdx.x] += sred[threadIdx.x + off];
            __syncthreads();
        }
        if (threadIdx.x == 0) bsum[cb] = sred[0];
    }
}

// ---------------------------------------------------------------- scan_write + cursor
// Phase 0: every block scans the nb (<256) raw block sums in LDS -> its global base.
// Phase A: block-local scan of inc -> row_ptr. Phase B: threads 0..127 write
// per-(range,slice) cursors from the dst histogram prefix. Block 0 zeroes gsum.
__global__ __launch_bounds__(256) void k_scan_write(const int* __restrict__ inc,
                                                    const int* __restrict__ bsum,
                                                    const unsigned* __restrict__ partial,
                                                    int* __restrict__ row_ptr,
                                                    int* __restrict__ cur,
                                                    float* __restrict__ gsum, int N) {
    __shared__ int sb[256];
    __shared__ int s[256];
    __shared__ int exs[256];
    int nb = (N + 255) / 256;
    int t = threadIdx.x;

    // phase 0: exclusive-scan block sums
    int bv = (t < nb) ? bsum[t] : 0;
    sb[t] = bv;
    __syncthreads();
    for (int off = 1; off < 256; off <<= 1) {
        int u = (t >= off) ? sb[t - off] : 0;
        __syncthreads();
        sb[t] += u;
        __syncthreads();
    }
    int excl = sb[t] - bv;
    __syncthreads();
    sb[t] = excl;
    __syncthreads();
    int blockBase = sb[blockIdx.x];

    // phase A: local scan of inc
    int B = blockIdx.x * 256;
    int i = B + t;
    int v = (i < N) ? inc[i] : 0;
    s[t] = v;
    __syncthreads();
    for (int off = 1; off < 256; off <<= 1) {
        int u = (t >= off) ? s[t - off] : 0;
        __syncthreads();
        s[t] += u;
        __syncthreads();
    }
    int ex = blockBase + s[t] - v;  // global exclusive prefix
    exs[t] = ex;
    if (i < N) row_ptr[i] = ex;
    if (i == N - 1) row_ptr[N] = ex + v;
    if (blockIdx.x == 0) {
        for (int j = t; j < GRAPHS * DIM; j += 256) gsum[j] = 0.0f;
    }
    __syncthreads();

    // phase B: per-slice cursors
    if (t < 128) {
        int n0 = B + 2 * t;
        if (n0 < N) {
            int r = n0 / NPR;
            int w = (n0 % NPR) >> 1;
            const unsigned* p = partial + ((size_t)(HIST_R + r) * HIST_S) * LDSW + w;
            int run0 = exs[2 * t];
            int run1 = exs[2 * t + 1];
            int* c = cur + (size_t)r * HIST_S * NPR + 2 * w;
#pragma unroll
            for (int sl = 0; sl < HIST_S; ++sl) {
                c[(size_t)sl * NPR + 0] = run0;
                c[(size_t)sl * NPR + 1] = run1;
                unsigned hv = p[(size_t)sl * LDSW];
                run0 += (int)(hv & 0xFFFFu);
                run1 += (int)(hv >> 16);
            }
        }
    }
}

// ---------------------------------------------------------------- CSR fill (LDS cursors)
__global__ __launch_bounds__(256) void k_fill2(const int* __restrict__ src,
                                               const int* __restrict__ dst,
                                               const int* __restrict__ cur,
                                               int* __restrict__ csr, int E) {
    __shared__ int lcur[NPR];   // 50 KB
    int r = blockIdx.x / HIST_S;
    int s = blockIdx.x % HIST_S;
    const int* cs = cur + (size_t)(r * HIST_S + s) * NPR;
    for (int i = threadIdx.x; i < NPR; i += 256) lcur[i] = cs[i];
    __syncthreads();
    int chunk = (E + HIST_S - 1) / HIST_S;
    int e0 = s * chunk;
    int e1 = min(e0 + chunk, E);
    unsigned base = (unsigned)(r * NPR);
    for (int i = e0 + threadIdx.x; i < e1; i += 256) {
        unsigned d = (unsigned)dst[i] - base;
        if (d < NPR) {
            int p = atomicAdd(&lcur[d], 1);   // LDS atomic
            csr[p] = src[i];
        }
    }
}

// ---------------------------------------------------------------- prep: h->fp16(h*ns), W1..3->fp16^T
__global__ void k_prep(const float4* __restrict__ h, const float* __restrict__ ns,
                       uint2* __restrict__ A,
                       const float* __restrict__ W1, const float* __restrict__ W2,
                       const float* __restrict__ W3, _Float16* __restrict__ Wt1,
                       _Float16* __restrict__ Wt2, _Float16* __restrict__ Wt3, int N) {
    int i = blockIdx.x * blockDim.x + threadIdx.x;
    int nf4 = N * 32;
    if (i < nf4) {
        int n = i >> 5;
        float s = ns[n];
        float4 v = h[i];
        __half2 p0 = __floats2half2_rn(v.x * s, v.y * s);
        __half2 p1 = __floats2half2_rn(v.z * s, v.w * s);
        uint2 o;
        o.x = *(unsigned*)&p0;
        o.y = *(unsigned*)&p1;
        A[i] = o;
    } else {
        int j = i - nf4;               // 0 .. 3*16384-1
        if (j < 3 * 16384) {
            int which = j >> 14;
            int local = j & 16383;
            int k = local >> 7;
            int n = local & 127;
            const float* W = (which == 0) ? W1 : (which == 1) ? W2 : W3;
            _Float16* Wt = (which == 0) ? Wt1 : (which == 1) ? Wt2 : Wt3;
            Wt[(size_t)n * DIM + k] = (_Float16)W[local];
        }
    }
}

// ---------------------------------------------------------------- aggregation (R10/R15 form)
// One wave per node, paired edges (lanes 0-31: even, 32-63: odd). Single clamped
// 16-edge round: 8 gathers in flight per lane, indices clamped to e1-1 (legal),
// accumulation predicated on e < e1. R15: the 16 edge indices of a round are loaded
// once by lane&15 (1 VMEM) and shfl-broadcast (was 8x 32-way-duplicate VMEM loads).
__global__ __launch_bounds__(256) void k_agg(const uint2* __restrict__ A,
                                             const int* __restrict__ row_ptr,
                                             const int* __restrict__ csr,
                                             const float* __restrict__ nd,
                                             uint2* __restrict__ Bh, int N) {
    int gtid = blockIdx.x * blockDim.x + threadIdx.x;
    int node = gtid >> 6;
    int lane = threadIdx.x & 63;
    if (node >= N) return;
    int e0 = row_ptr[node];
    int e1 = row_ptr[node + 1];
    int half = lane >> 5;    // 0: even edge, 1: odd edge
    int l8 = lane & 31;      // 8-byte slot within 256B row
    float ax = 0.f, ay = 0.f, az = 0.f, aw = 0.f;

    for (int base = e0; base < e1; base += 16) {
        int vl = csr[min(base + (lane & 15), e1 - 1)];   // lanes 0-15 hold the 16 indices
        int idx[8];
        uint2 u[8];
#pragma unroll
        for (int j = 0; j < 8; ++j) {
            idx[j] = __shfl(vl, 2 * j + half);
        }
#pragma unroll
        for (int j = 0; j < 8; ++j) {
            u[j] = A[(size_t)idx[j] * 32 + l8];
        }
#pragma unroll
        for (int j = 0; j < 8; ++j) {
            int ee = base + 2 * j + half;
            if (ee < e1) {
                __half2 p0 = *(__half2*)&u[j].x;
                __half2 p1 = *(__half2*)&u[j].y;
                float2 f0 = __half22float2(p0);
                float2 f1 = __half22float2(p1);
                ax += f0.x; ay += f0.y; az += f1.x; aw += f1.y;
            }
        }
    }

    ax += __shfl_xor(ax, 32);
    ay += __shfl_xor(ay, 32);
    az += __shfl_xor(az, 32);
    aw += __shfl_xor(aw, 32);

    if (half == 0) {
        float scale = nd[node];
        __half2 p0 = __floats2half2_rn(ax * scale, ay * scale);
        __half2 p1 = __floats2half2_rn(az * scale, aw * scale);
        uint2 o;
        o.x = *(unsigned*)&p0;
        o.y = *(unsigned*)&p1;
        Bh[(size_t)node * 32 + l8] = o;
    }
}

// ---------------------------------------------------------------- GEMM on matrix cores (R15 transposed roles)
// X[node][f] = relu(Bin[node][:] @ W + b)[f], computed as D = Wt_frag * node_frag:
// A operand: lane=Wt[m=c*16+l16][k=q*32+quad*8+j]  (m = output feature)
// B operand: lane=Bin[node=blk*64+wave*16+l16][k=q*32+quad*8+j]
// C/D: col(l16)=node, row(quad*4+r)=feature -> thread owns node x 4 consecutive feats
// per c-tile: 8x half4 8B stores. SCALE_NS multiplies by ns[node] (layers 1-2).
template <bool SCALE_NS>
__global__ __launch_bounds__(256) void k_gemm_t(
    const _Float16* __restrict__ Bin, const _Float16* __restrict__ Wt,
    const float* __restrict__ bias, const float* __restrict__ ns,
    _Float16* __restrict__ Xout, int N) {
    int tid = threadIdx.x;
    int wave = tid >> 6;
    int lane = tid & 63;
    int quad = lane >> 4;
    int l16 = lane & 15;
    int node = blockIdx.x * 64 + wave * 16 + l16;

    half8 b[4];
#pragma unroll
    for (int q = 0; q < 4; ++q) {
        if (node < N) {
            b[q] = *(const half8*)&Bin[(size_t)node * DIM + q * 32 + quad * 8];
        } else {
            b[q] = half8{0, 0, 0, 0, 0, 0, 0, 0};
        }
    }

    floatx4 acc[8];
#pragma unroll
    for (int c = 0; c < 8; ++c) acc[c] = floatx4{0.f, 0.f, 0.f, 0.f};

#pragma unroll
    for (int c = 0; c < 8; ++c) {
#pragma unroll
        for (int q = 0; q < 4; ++q) {
            half8 a = *(const half8*)&Wt[(size_t)(c * 16 + l16) * DIM + q * 32 + quad * 8];
            acc[c] = __builtin_amdgcn_mfma_f32_16x16x32_f16(a, b[q], acc[c], 0, 0, 0);
        }
    }

    if (node < N) {
        float s = SCALE_NS ? ns[node] : 1.0f;
#pragma unroll
        for (int c = 0; c < 8; ++c) {
            float4 b4 = *(const float4*)&bias[c * 16 + quad * 4];
            half4 o;
            o[0] = (_Float16)(fmaxf(acc[c][0] + b4.x, 0.0f) * s);
            o[1] = (_Float16)(fmaxf(acc[c][1] + b4.y, 0.0f) * s);
            o[2] = (_Float16)(fmaxf(acc[c][2] + b4.z, 0.0f) * s);
            o[3] = (_Float16)(fmaxf(acc[c][3] + b4.w, 0.0f) * s);
            *(half4*)&Xout[(size_t)node * DIM + c * 16 + quad * 4] = o;
        }
    }
}

// ---------------------------------------------------------------- layer-3 GEMM fused with pooling
// Same MFMA body as k_gemm_t<false>, epilogue pools directly from fp32 acc:
// graph_ids are SORTED, so a wave's 16-node tile is graph-uniform unless it straddles
// a boundary (check gid endpoints). Uniform: 4-step shfl_xor reduce over l16 ->
// 1 LDS atomic per (quad,c,r). Block flushes its <=PBINS graph bins with one global
// atomic per (graph, feature). Fallback (block spans >=PBINS graphs — never at
// N/G=781 nodes/graph): per-lane global atomics.
#define PBINS 8
__global__ __launch_bounds__(256) void k_gemm_pool(
    const _Float16* __restrict__ Bin, const _Float16* __restrict__ Wt,
    const float* __restrict__ bias, const int* __restrict__ gid,
    float* __restrict__ gsum, int N) {
    __shared__ float lsum[PBINS * DIM];   // 4 KB
    int tid = threadIdx.x;
    for (int i = tid; i < PBINS * DIM; i += 256) lsum[i] = 0.0f;
    int wave = tid >> 6;
    int lane = tid & 63;
    int quad = lane >> 4;
    int l16 = lane & 15;
    int r0 = blockIdx.x * 64;
    int node = r0 + wave * 16 + l16;
    int nodec = min(node, N - 1);

    half8 b[4];
#pragma unroll
    for (int q = 0; q < 4; ++q) {
        if (node < N) {
            b[q] = *(const half8*)&Bin[(size_t)node * DIM + q * 32 + quad * 8];
        } else {
            b[q] = half8{0, 0, 0, 0, 0, 0, 0, 0};
        }
    }

    floatx4 acc[8];
#pragma unroll
    for (int c = 0; c < 8; ++c) acc[c] = floatx4{0.f, 0.f, 0.f, 0.f};
    __syncthreads();   // lsum zeros visible before any atomic below

#pragma unroll
    for (int c = 0; c < 8; ++c) {
#pragma unroll
        for (int q = 0; q < 4; ++q) {
            half8 a = *(const half8*)&Wt[(size_t)(c * 16 + l16) * DIM + q * 32 + quad * 8];
            acc[c] = __builtin_amdgcn_mfma_f32_16x16x32_f16(a, b[q], acc[c], 0, 0, 0);
        }
    }

    int g = gid[nodec];
    int g0b = gid[r0];                          // r0 < N for every block
    int gEb = gid[min(r0 + 63, N - 1)];
    bool ldsPath = (gEb - g0b) < PBINS;         // block-uniform
    int gF = __shfl(g, 0);                      // graph of wave-tile node 0
    int gL = __shfl(g, 15);                     // graph of wave-tile node 15
    bool uni = (gF == gL);                      // wave-uniform
    float valid = (node < N) ? 1.0f : 0.0f;     // zero padded-node contribution (relu(bias)!=0)

#pragma unroll
    for (int c = 0; c < 8; ++c) {
        float4 b4 = *(const float4*)&bias[c * 16 + quad * 4];
        float bv[4] = {b4.x, b4.y, b4.z, b4.w};
#pragma unroll
        for (int r = 0; r < 4; ++r) {
            float v = fmaxf(acc[c][r] + bv[r], 0.0f) * valid;
            int f = c * 16 + quad * 4 + r;
            if (ldsPath) {
                if (uni) {
                    v += __shfl_xor(v, 1);
                    v += __shfl_xor(v, 2);
                    v += __shfl_xor(v, 4);
                    v += __shfl_xor(v, 8);      // sum over the 16 nodes of the tile
                    if (l16 == 0) atomicAdd(&lsum[(gF - g0b) * DIM + f], v);
                } else {
                    if (node < N) atomicAdd(&lsum[(g - g0b) * DIM + f], v);
                }
            } else {
                if (node < N) atomicAdd(&gsum[(size_t)g * DIM + f], v);
            }
        }
    }
    __syncthreads();
    if (ldsPath) {
        int ng = gEb - g0b + 1;
        for (int i = tid; i < ng * DIM; i += 256) {
            float sv = lsum[i];
            if (sv != 0.0f) atomicAdd(&gsum[(size_t)g0b * DIM + i], sv);
        }
    }
}

// ---------------------------------------------------------------- finalize (count via binary search)
__global__ void k_finalize(const float* __restrict__ gsum, const int* __restrict__ gid,
                           float* __restrict__ out, int N, int G) {
    int i = blockIdx.x * blockDim.x + threadIdx.x;
    if (i < G * DIM) {
        int g = i >> 7;
        int lo = 0, hi = N;                 // lower_bound(g)
        while (lo < hi) { int m = (lo + hi) >> 1; if (gid[m] < g) lo = m + 1; else hi = m; }
        int lo2 = lo, hi2 = N;              // lower_bound(g+1)
        while (lo2 < hi2) { int m = (lo2 + hi2) >> 1; if (gid[m] < g + 1) lo2 = m + 1; else hi2 = m; }
        float c = fmaxf((float)(lo2 - lo), 1.0f);
        out[i] = gsum[i] / c;
    }
}

// ---------------------------------------------------------------- launch
extern "C" void kernel_launch(void* const* d_in, const int* in_sizes, int n_in,
                              void* d_out, int out_size, void* d_ws, size_t ws_size,
                              hipStream_t stream) {
    const float* h   = (const float*)d_in[0];
    const int*   src = (const int*)d_in[1];
    const int*   dst = (const int*)d_in[2];
    const int*   gid = (const int*)d_in[3];
    const float* W1  = (const float*)d_in[4];
    const float* b1  = (const float*)d_in[5];
    const float* W2  = (const float*)d_in[6];
    const float* b2  = (const float*)d_in[7];
    const float* W3  = (const float*)d_in[8];
    const float* b3  = (const float*)d_in[9];

    const int N = in_sizes[0] / DIM;   // 50000
    const int E = in_sizes[1];         // 600000
    const int G = GRAPHS;
    float* out = (float*)d_out;

    char* ws = (char*)d_ws;
    size_t off = 0;
    auto alloc = [&](size_t bytes) -> void* {
        void* p = ws + off;
        off += (bytes + 255) & ~(size_t)255;
        return p;
    };
    const int nb = (N + 255) / 256;    // 196
    uint2* Ah0     = (uint2*)alloc((size_t)N * DIM * 2);  // fp16 gather operand (ping)
    uint2* Ah1     = (uint2*)alloc((size_t)N * DIM * 2);  // fp16 pong
    uint2* Bh      = (uint2*)alloc((size_t)N * DIM * 2);  // agg output (fp16)
    _Float16* Wt1  = (_Float16*)alloc((size_t)DIM * DIM * 2);
    _Float16* Wt2  = (_Float16*)alloc((size_t)DIM * DIM * 2);
    _Float16* Wt3  = (_Float16*)alloc((size_t)DIM * DIM * 2);
    float* ns      = (float*)alloc((size_t)N * 4);
    float* nd      = (float*)alloc((size_t)N * 4);
    int*   inc     = (int*)alloc((size_t)N * 4);
    unsigned* partial = (unsigned*)alloc((size_t)2 * HIST_R * HIST_S * LDSW * 4);  // 12.8 MB
    int*   cur     = (int*)alloc((size_t)HIST_R * HIST_S * NPR * 4);               // 12.8 MB
    int*   row_ptr = (int*)alloc((size_t)(N + 1) * 4);
    int*   csr     = (int*)alloc((size_t)E * 4);
    float* gsum    = (float*)alloc((size_t)G * DIM * 4);
    int*   bsum    = (int*)alloc((size_t)nb * 4);

    // degrees via LDS histograms (no global atomics)
    k_hist<<<2 * HIST_R * HIST_S, 256, 0, stream>>>(src, dst, partial, E);
    // merge -> ns/nd/inc + per-block sums
    k_hist_merge<<<2 * nb, 256, 0, stream>>>(partial, ns, nd, inc, bsum, N);
    // row_ptr + per-(range,slice) cursors + gsum zero (scan_top + cursor folded in)
    k_scan_write<<<nb, 256, 0, stream>>>(inc, bsum, partial, row_ptr, cur, gsum, N);
    k_fill2<<<HIST_R * HIST_S, 256, 0, stream>>>(src, dst, cur, csr, E);

    // Ah0 = fp16(h*ns) + weights -> fp16 transposed (single launch)
    int prepThreads = N * 32 + 3 * 16384;
    k_prep<<<(prepThreads + 255) / 256, 256, 0, stream>>>((const float4*)h, ns, Ah0,
                                                          W1, W2, W3, Wt1, Wt2, Wt3, N);

    int aggBlocks  = (N * 64 + 255) / 256;
    int gemmBlocks = (N + 63) / 64;

    // layer 1
    k_agg<<<aggBlocks, 256, 0, stream>>>(Ah0, row_ptr, csr, nd, Bh, N);
    k_gemm_t<true><<<gemmBlocks, 256, 0, stream>>>((const _Float16*)Bh, Wt1, b1, ns, (_Float16*)Ah1, N);
    // layer 2
    k_agg<<<aggBlocks, 256, 0, stream>>>(Ah1, row_ptr, csr, nd, Bh, N);
    k_gemm_t<true><<<gemmBlocks, 256, 0, stream>>>((const _Float16*)Bh, Wt2, b2, ns, (_Float16*)Ah0, N);
    // layer 3: agg + GEMM fused with pooling (X3 eliminated)
    k_agg<<<aggBlocks, 256, 0, stream>>>(Ah0, row_ptr, csr, nd, Bh, N);
    k_gemm_pool<<<gemmBlocks, 256, 0, stream>>>((const _Float16*)Bh, Wt3, b3, gid, gsum, N);

    k_finalize<<<(G * DIM + 255) / 256, 256, 0, stream>>>(gsum, gid, out, N, G);
}